// Round 6
// baseline (40.057 us; speedup 1.0000x reference)
//
#include <hip/hip_runtime.h>
#include <hip/hip_bf16.h>

// ExtraMSAEmbedding: out[p, o] = W[o, msa[p]] + hd[p]*W[o,23] + dv[p]*W[o,24] + b[o]
// p = flattened (seq, res) position, 2048*384 = 786432 positions, o in [0,64).
// Write-bound: 201 MB f32 output vs ~9.4 MB input reads. Floor ~33.5 us @ 6.3 TB/s.
// R2/R3/R5 (grid-stride / one-shot / persistent-pipelined) all ~37.4-37.9 us.
// This version: remapped so each WAVE stores 32 consecutive positions -> its 8
// store instructions form one sequential 8 KB run (max DRAM burst locality),
// instead of 1 KB chunks at 4 KB stride.

#define C_IN   25
#define C_OUT  64
#define TPAD   68   // row stride in floats: 272 B, 16B-aligned
#define UNROLL 8    // stores per thread; block covers 128 positions

typedef float v4f __attribute__((ext_vector_type(4)));

__global__ __launch_bounds__(256) void extra_msa_emb_kernel(
    const int* __restrict__ msa,
    const float* __restrict__ hd,
    const float* __restrict__ dv,
    const float* __restrict__ W,   // [64, 25] row-major
    const float* __restrict__ b,   // [64]
    float* __restrict__ out) {     // [npos, 64]
    const int tid = threadIdx.x;

    // Table first (W/b loads oldest in vmem FIFO — R4 lesson).
    // T[c][o] = W[o*25+c] (+ b[o] when c < 23), transposed + padded.
    __shared__ float T[C_IN][TPAD];
    for (int idx = tid; idx < C_IN * C_OUT; idx += 256) {
        const int c  = idx >> 6;
        const int oo = idx & 63;
        float v = W[oo * C_IN + c];
        if (c < 23) v += b[oo];
        T[c][oo] = v;
    }
    __syncthreads();

    const int w      = tid >> 6;        // wave 0..3: owns 32 consecutive positions
    const int g      = (tid >> 4) & 3;  // sub-group within wave
    const int lane16 = tid & 15;        // 16 threads per position
    const int o      = lane16 * 4;      // each thread owns 4 consecutive outputs

    // Wave w covers positions [blockbase + 32w, +32); store j covers
    // positions 4j..4j+3 -> 8 sequential 1 KB stores = one 8 KB run.
    const int pbase = blockIdx.x * 128 + w * 32 + g;

    int   cls[UNROLL];
    float h[UNROLL], d[UNROLL];
#pragma unroll
    for (int j = 0; j < UNROLL; ++j) {
        const int p = pbase + j * 4;
        cls[j] = msa[p];
        h[j]   = hd[p];
        d[j]   = dv[p];
    }

    const v4f w23 = *reinterpret_cast<const v4f*>(&T[23][o]);
    const v4f w24 = *reinterpret_cast<const v4f*>(&T[24][o]);

    v4f t[UNROLL];
#pragma unroll
    for (int j = 0; j < UNROLL; ++j)
        t[j] = *reinterpret_cast<const v4f*>(&T[cls[j]][o]);

#pragma unroll
    for (int j = 0; j < UNROLL; ++j) {
        const v4f r = t[j] + h[j] * w23 + d[j] * w24;
        const long long p = (long long)(pbase + j * 4);
        __builtin_nontemporal_store(r, reinterpret_cast<v4f*>(&out[p * C_OUT + o]));
    }
}

extern "C" void kernel_launch(void* const* d_in, const int* in_sizes, int n_in,
                              void* d_out, int out_size, void* d_ws, size_t ws_size,
                              hipStream_t stream) {
    const int*   msa = (const int*)d_in[0];
    const float* hd  = (const float*)d_in[1];
    const float* dv  = (const float*)d_in[2];
    const float* W   = (const float*)d_in[3];
    const float* b   = (const float*)d_in[4];
    float* out = (float*)d_out;

    const int npos = in_sizes[0];  // 2048 * 384 = 786432, divisible by 128

    const int block = 256;
    const int grid  = npos / 128;  // 6144 blocks, one 128-position chunk each
    extra_msa_emb_kernel<<<grid, block, 0, stream>>>(msa, hd, dv, W, b, out);
}